// Round 3
// baseline (257.874 us; speedup 1.0000x reference)
//
#include <hip/hip_runtime.h>
#include <math.h>

#define B_ 256
#define M_ 3
#define L_ 100000
#define A_ 4096
#define H_ 512
#define MA_ (M_*A_)          // 12288 = K for GEMM1
#define K1_ MA_
#define NZ_ 16               // split-K chunks for GEMM1
#define KC1_ (K1_/NZ_)       // 768
#define BCHUNK_ 4

typedef __attribute__((ext_vector_type(8))) short bf16x8;
typedef __attribute__((ext_vector_type(4))) float f32x4;

static __device__ __forceinline__ float4 ld4(const float* p) {
    return *reinterpret_cast<const float4*>(p);
}
static __device__ __forceinline__ void st4(float* p, float4 v) {
    *reinterpret_cast<float4*>(p) = v;
}
static __device__ __forceinline__ unsigned short f2bf(float f) {
    unsigned u = __float_as_uint(f);
    unsigned r = (u + 0x7FFFu + ((u >> 16) & 1u)) >> 16;
    return (unsigned short)r;
}
// convert 8 consecutive fp32 (2 float4) to a bf16x8 fragment
static __device__ __forceinline__ bf16x8 cvt8(float4 a, float4 b) {
    bf16x8 o;
    o[0] = (short)f2bf(a.x); o[1] = (short)f2bf(a.y);
    o[2] = (short)f2bf(a.z); o[3] = (short)f2bf(a.w);
    o[4] = (short)f2bf(b.x); o[5] = (short)f2bf(b.y);
    o[6] = (short)f2bf(b.z); o[7] = (short)f2bf(b.w);
    return o;
}
static __device__ __forceinline__ float getc(const float4& v, int c) {
    switch (c) { case 0: return v.x; case 1: return v.y; case 2: return v.z; default: return v.w; }
}

__global__ void init_head(int* __restrict__ head) {
    int i = blockIdx.x * blockDim.x + threadIdx.x;
    if (i < L_ / 4) *reinterpret_cast<int4*>(head + i * 4) = make_int4(-1, -1, -1, -1);
}

__global__ void build_chain(const int* __restrict__ idx, int* __restrict__ head,
                            int* __restrict__ next) {
    int a = blockIdx.x * blockDim.x + threadIdx.x;
    if (a < A_) next[a] = atomicExch(&head[idx[a]], a);
}

// Fused: logits[b,l] = sum_m x[b,m,l]*(softmax(gl)[m]+dw[m,l]) + bias[l]
// + gather x_active[b, m*A+a] = bf16(x[b,m,idx[a]]) via head/next chain map.
// 8 floats per thread along l, BCHUNK=4 -> 24 float4 loads in flight.
__global__ __launch_bounds__(256) void logits_gather(
    const float* __restrict__ x, const float* __restrict__ gl,
    const float* __restrict__ dw, const float* __restrict__ bias,
    const int* __restrict__ head, const int* __restrict__ next,
    float* __restrict__ logits, unsigned short* __restrict__ xa) {
    const int L8 = L_ / 8;   // 12500
    int i = blockIdx.x * blockDim.x + threadIdx.x;
    if (i >= L8) return;
    int l = i * 8;
    int b0 = blockIdx.y * BCHUNK_;

    float g0 = gl[0], g1 = gl[1], g2 = gl[2];
    float mx = fmaxf(g0, fmaxf(g1, g2));
    float e0 = expf(g0 - mx), e1 = expf(g1 - mx), e2 = expf(g2 - mx);
    float inv = 1.0f / (e0 + e1 + e2);
    float sm[3] = {e0 * inv, e1 * inv, e2 * inv};

    float4 w[3][2], bb[2];
    #pragma unroll
    for (int m = 0; m < 3; ++m) {
        float4 dA = ld4(dw + (size_t)m * L_ + l);
        float4 dB = ld4(dw + (size_t)m * L_ + l + 4);
        w[m][0] = make_float4(sm[m] + dA.x, sm[m] + dA.y, sm[m] + dA.z, sm[m] + dA.w);
        w[m][1] = make_float4(sm[m] + dB.x, sm[m] + dB.y, sm[m] + dB.z, sm[m] + dB.w);
    }
    bb[0] = ld4(bias + l);
    bb[1] = ld4(bias + l + 4);

    int heads[8];
    *reinterpret_cast<int4*>(heads) = *reinterpret_cast<const int4*>(head + l);
    *reinterpret_cast<int4*>(heads + 4) = *reinterpret_cast<const int4*>(head + l + 4);

    float4 X[BCHUNK_][3][2];
    #pragma unroll
    for (int c = 0; c < BCHUNK_; ++c) {
        const float* xb = x + (size_t)(b0 + c) * M_ * L_ + l;
        #pragma unroll
        for (int m = 0; m < 3; ++m) {
            X[c][m][0] = ld4(xb + (size_t)m * L_);
            X[c][m][1] = ld4(xb + (size_t)m * L_ + 4);
        }
    }
    #pragma unroll
    for (int c = 0; c < BCHUNK_; ++c) {
        #pragma unroll
        for (int hh = 0; hh < 2; ++hh) {
            float4 o;
            o.x = X[c][0][hh].x * w[0][hh].x + X[c][1][hh].x * w[1][hh].x + X[c][2][hh].x * w[2][hh].x + bb[hh].x;
            o.y = X[c][0][hh].y * w[0][hh].y + X[c][1][hh].y * w[1][hh].y + X[c][2][hh].y * w[2][hh].y + bb[hh].y;
            o.z = X[c][0][hh].z * w[0][hh].z + X[c][1][hh].z * w[1][hh].z + X[c][2][hh].z * w[2][hh].z + bb[hh].z;
            o.w = X[c][0][hh].w * w[0][hh].w + X[c][1][hh].w * w[1][hh].w + X[c][2][hh].w * w[2][hh].w + bb[hh].w;
            st4(logits + (size_t)(b0 + c) * L_ + l + hh * 4, o);
        }
    }

    // gather (rare: ~4% of labels active)
    #pragma unroll
    for (int p = 0; p < 8; ++p) {
        int a = heads[p];
        int hh = p >> 2, c = p & 3;
        while (a >= 0) {
            #pragma unroll
            for (int b = 0; b < BCHUNK_; ++b) {
                unsigned short* xab = xa + (size_t)(b0 + b) * MA_;
                xab[a]          = f2bf(getc(X[b][0][hh], c));
                xab[A_ + a]     = f2bf(getc(X[b][1][hh], c));
                xab[2 * A_ + a] = f2bf(getc(X[b][2][hh], c));
            }
            a = next[a];
        }
    }
}

// GEMM1 split-K MFMA: part[z,b,n] = sum_{k in chunk z} xa[b,k] * hw[n,k]
// W read as fp32 and converted in-register (no separate conversion pass).
__global__ __launch_bounds__(256) void gemm1_mfma(
    const unsigned short* __restrict__ Xa, const float* __restrict__ W,
    float* __restrict__ part) {
    int tid = threadIdx.x;
    int wave = tid >> 6, lane = tid & 63;
    int row0 = blockIdx.x * 64 + (wave >> 1) * 32;
    int col0 = blockIdx.y * 64 + (wave & 1) * 32;
    int k0 = blockIdx.z * KC1_;
    int lr = lane & 15;
    int lk = (lane >> 4) * 8;
    const unsigned short* pa0 = Xa + (size_t)(row0 + lr) * K1_ + k0 + lk;
    const unsigned short* pa1 = pa0 + (size_t)16 * K1_;
    const float* pb0 = W + (size_t)(col0 + lr) * K1_ + k0 + lk;
    const float* pb1 = pb0 + (size_t)16 * K1_;
    f32x4 acc00 = {0.f,0.f,0.f,0.f}, acc01 = {0.f,0.f,0.f,0.f};
    f32x4 acc10 = {0.f,0.f,0.f,0.f}, acc11 = {0.f,0.f,0.f,0.f};
    #pragma unroll 4
    for (int k = 0; k < KC1_; k += 32) {
        bf16x8 a0 = *reinterpret_cast<const bf16x8*>(pa0 + k);
        bf16x8 a1 = *reinterpret_cast<const bf16x8*>(pa1 + k);
        bf16x8 b0 = cvt8(ld4(pb0 + k), ld4(pb0 + k + 4));
        bf16x8 b1 = cvt8(ld4(pb1 + k), ld4(pb1 + k + 4));
        acc00 = __builtin_amdgcn_mfma_f32_16x16x32_bf16(a0, b0, acc00, 0, 0, 0);
        acc01 = __builtin_amdgcn_mfma_f32_16x16x32_bf16(a0, b1, acc01, 0, 0, 0);
        acc10 = __builtin_amdgcn_mfma_f32_16x16x32_bf16(a1, b0, acc10, 0, 0, 0);
        acc11 = __builtin_amdgcn_mfma_f32_16x16x32_bf16(a1, b1, acc11, 0, 0, 0);
    }
    float* base = part + (size_t)blockIdx.z * B_ * H_;
    #pragma unroll
    for (int j = 0; j < 4; ++j) {
        int r = (lane >> 4) * 4 + j;   // C/D: col=lane&15, row=(lane>>4)*4+j
        base[(size_t)(row0 + r) * H_ + col0 + lr]           = acc00[j];
        base[(size_t)(row0 + r) * H_ + col0 + 16 + lr]      = acc01[j];
        base[(size_t)(row0 + 16 + r) * H_ + col0 + lr]      = acc10[j];
        base[(size_t)(row0 + 16 + r) * H_ + col0 + 16 + lr] = acc11[j];
    }
}

// h[b,n] = bf16(relu(sum_z part[z,b,n] + hb[n]))
__global__ void reduce_relu(const float* __restrict__ part,
                            const float* __restrict__ hb,
                            unsigned short* __restrict__ h) {
    int t = blockIdx.x * blockDim.x + threadIdx.x;
    if (t >= B_ * H_) return;
    int n = t & (H_ - 1);
    float s = hb[n];
    #pragma unroll
    for (int z = 0; z < NZ_; ++z) s += part[(size_t)z * B_ * H_ + t];
    h[t] = f2bf(fmaxf(s, 0.0f));
}

// GEMM2 + fused scatter: logits[b, idx[a]] += alpha*(sum_n h[b,n]*W2[a,n] + b2[a])
// W2 read as fp32, converted in-register. Scatter via atomicAdd (duplicate
// labels are rare; pairwise fp add is commutative).
__global__ __launch_bounds__(256) void gemm2_scatter(
    const unsigned short* __restrict__ Hm, const float* __restrict__ W2,
    const float* __restrict__ b2, const float* __restrict__ la,
    const int* __restrict__ idx, float* __restrict__ logits) {
    int tid = threadIdx.x;
    int wave = tid >> 6, lane = tid & 63;
    int row0 = blockIdx.x * 64 + (wave >> 1) * 32;
    int col0 = blockIdx.y * 64 + (wave & 1) * 32;
    int lr = lane & 15;
    int lk = (lane >> 4) * 8;
    const unsigned short* pa0 = Hm + (size_t)(row0 + lr) * H_ + lk;
    const unsigned short* pa1 = pa0 + (size_t)16 * H_;
    const float* pb0 = W2 + (size_t)(col0 + lr) * H_ + lk;
    const float* pb1 = pb0 + (size_t)16 * H_;
    f32x4 acc00 = {0.f,0.f,0.f,0.f}, acc01 = {0.f,0.f,0.f,0.f};
    f32x4 acc10 = {0.f,0.f,0.f,0.f}, acc11 = {0.f,0.f,0.f,0.f};
    #pragma unroll 4
    for (int k = 0; k < H_; k += 32) {
        bf16x8 a0 = *reinterpret_cast<const bf16x8*>(pa0 + k);
        bf16x8 a1 = *reinterpret_cast<const bf16x8*>(pa1 + k);
        bf16x8 b0 = cvt8(ld4(pb0 + k), ld4(pb0 + k + 4));
        bf16x8 b1 = cvt8(ld4(pb1 + k), ld4(pb1 + k + 4));
        acc00 = __builtin_amdgcn_mfma_f32_16x16x32_bf16(a0, b0, acc00, 0, 0, 0);
        acc01 = __builtin_amdgcn_mfma_f32_16x16x32_bf16(a0, b1, acc01, 0, 0, 0);
        acc10 = __builtin_amdgcn_mfma_f32_16x16x32_bf16(a1, b0, acc10, 0, 0, 0);
        acc11 = __builtin_amdgcn_mfma_f32_16x16x32_bf16(a1, b1, acc11, 0, 0, 0);
    }
    float alpha = 0.1f / (1.0f + expf(-la[0]));
    int c0 = col0 + lr, c1 = col0 + 16 + lr;
    int l0 = idx[c0], l1 = idx[c1];
    float bias0 = b2[c0], bias1 = b2[c1];
    #pragma unroll
    for (int j = 0; j < 4; ++j) {
        int r = (lane >> 4) * 4 + j;
        atomicAdd(&logits[(size_t)(row0 + r) * L_ + l0],      alpha * (acc00[j] + bias0));
        atomicAdd(&logits[(size_t)(row0 + r) * L_ + l1],      alpha * (acc01[j] + bias1));
        atomicAdd(&logits[(size_t)(row0 + 16 + r) * L_ + l0], alpha * (acc10[j] + bias0));
        atomicAdd(&logits[(size_t)(row0 + 16 + r) * L_ + l1], alpha * (acc11[j] + bias1));
    }
}

static inline size_t align256(size_t x) { return (x + 255) & ~(size_t)255; }

extern "C" void kernel_launch(void* const* d_in, const int* in_sizes, int n_in,
                              void* d_out, int out_size, void* d_ws, size_t ws_size,
                              hipStream_t stream) {
    const float* x    = (const float*)d_in[0];
    const int*   idx  = (const int*)d_in[1];
    const float* gl   = (const float*)d_in[2];
    const float* dw   = (const float*)d_in[3];
    const float* bias = (const float*)d_in[4];
    const float* la   = (const float*)d_in[5];
    const float* hw   = (const float*)d_in[6];
    const float* hb   = (const float*)d_in[7];
    const float* w2   = (const float*)d_in[8];
    const float* b2   = (const float*)d_in[9];
    float* logits = (float*)d_out;

    char* ws = (char*)d_ws;
    int* head = (int*)ws;                      ws += align256((size_t)L_ * 4);
    int* next = (int*)ws;                      ws += align256((size_t)A_ * 4);
    unsigned short* xa = (unsigned short*)ws;  ws += align256((size_t)B_ * MA_ * 2);
    float* part = (float*)ws;                  ws += align256((size_t)NZ_ * B_ * H_ * 4);
    unsigned short* h = (unsigned short*)ws;   ws += align256((size_t)B_ * H_ * 2);

    init_head<<<(L_ / 4 + 255) / 256, 256, 0, stream>>>(head);
    build_chain<<<(A_ + 255) / 256, 256, 0, stream>>>(idx, head, next);

    dim3 g1((L_ / 8 + 255) / 256, B_ / BCHUNK_);
    logits_gather<<<g1, 256, 0, stream>>>(x, gl, dw, bias, head, next, logits, xa);

    gemm1_mfma<<<dim3(B_ / 64, H_ / 64, NZ_), 256, 0, stream>>>(xa, hw, part);
    reduce_relu<<<(B_ * H_ + 255) / 256, 256, 0, stream>>>(part, hb, h);
    gemm2_scatter<<<dim3(B_ / 64, A_ / 64), 256, 0, stream>>>(h, w2, b2, la, idx, logits);
}

// Round 4
// 210.600 us; speedup vs baseline: 1.2245x; 1.2245x over previous
//
#include <hip/hip_runtime.h>
#include <math.h>

#define B_ 256
#define M_ 3
#define L_ 100000
#define A_ 4096
#define H_ 512
#define MA_ (M_*A_)          // 12288 = K for GEMM1
#define K1_ MA_
#define NZ_ 16               // split-K chunks for GEMM1
#define KC1_ (K1_/NZ_)       // 768
#define BCHUNK_ 4

typedef __attribute__((ext_vector_type(8))) short bf16x8;
typedef __attribute__((ext_vector_type(8))) unsigned short u16x8;
typedef __attribute__((ext_vector_type(4))) float f32x4;

static __device__ __forceinline__ float4 ld4(const float* p) {
    return *reinterpret_cast<const float4*>(p);
}
static __device__ __forceinline__ void st4(float* p, float4 v) {
    *reinterpret_cast<float4*>(p) = v;
}
static __device__ __forceinline__ unsigned short f2bf(float f) {
    unsigned u = __float_as_uint(f);
    unsigned r = (u + 0x7FFFu + ((u >> 16) & 1u)) >> 16;
    return (unsigned short)r;
}
static __device__ __forceinline__ bf16x8 cvt8(float4 a, float4 b) {
    bf16x8 o;
    o[0] = (short)f2bf(a.x); o[1] = (short)f2bf(a.y);
    o[2] = (short)f2bf(a.z); o[3] = (short)f2bf(a.w);
    o[4] = (short)f2bf(b.x); o[5] = (short)f2bf(b.y);
    o[6] = (short)f2bf(b.z); o[7] = (short)f2bf(b.w);
    return o;
}
static __device__ __forceinline__ float getc(const float4& v, int c) {
    switch (c) { case 0: return v.x; case 1: return v.y; case 2: return v.z; default: return v.w; }
}

__global__ void init_head(int* __restrict__ head) {
    int i = blockIdx.x * blockDim.x + threadIdx.x;
    if (i < L_ / 4) *reinterpret_cast<int4*>(head + i * 4) = make_int4(-1, -1, -1, -1);
}

__global__ void build_chain(const int* __restrict__ idx, int* __restrict__ head,
                            int* __restrict__ next) {
    int a = blockIdx.x * blockDim.x + threadIdx.x;
    if (a < A_) next[a] = atomicExch(&head[idx[a]], a);
}

__global__ void f32_to_bf16(const float* __restrict__ in, unsigned short* __restrict__ out, int n8) {
    int i = blockIdx.x * blockDim.x + threadIdx.x;
    if (i >= n8) return;
    float4 v0 = ld4(in + (size_t)i * 8);
    float4 v1 = ld4(in + (size_t)i * 8 + 4);
    u16x8 o;
    o[0] = f2bf(v0.x); o[1] = f2bf(v0.y); o[2] = f2bf(v0.z); o[3] = f2bf(v0.w);
    o[4] = f2bf(v1.x); o[5] = f2bf(v1.y); o[6] = f2bf(v1.z); o[7] = f2bf(v1.w);
    *reinterpret_cast<u16x8*>(out + (size_t)i * 8) = o;
}

// Fused: logits[b,l] = sum_m x[b,m,l]*(softmax(gl)[m]+dw[m,l]) + bias[l]
// + gather x_active[b, m*A+a] = bf16(x[b,m,idx[a]]) via head/next chain map.
// R2-proven shape: 4 floats/thread along l, BCHUNK=4 unrolled -> 12 float4
// loads in flight at VGPR~44 (occupancy ~46%).
__global__ __launch_bounds__(256) void logits_gather(
    const float* __restrict__ x, const float* __restrict__ gl,
    const float* __restrict__ dw, const float* __restrict__ bias,
    const int* __restrict__ head, const int* __restrict__ next,
    float* __restrict__ logits, unsigned short* __restrict__ xa) {
    const int L4 = L_ / 4;
    int i = blockIdx.x * blockDim.x + threadIdx.x;
    if (i >= L4) return;
    int l = i * 4;
    int b0 = blockIdx.y * BCHUNK_;

    float g0 = gl[0], g1 = gl[1], g2 = gl[2];
    float mx = fmaxf(g0, fmaxf(g1, g2));
    float e0 = expf(g0 - mx), e1 = expf(g1 - mx), e2 = expf(g2 - mx);
    float inv = 1.0f / (e0 + e1 + e2);
    float s0 = e0 * inv, s1 = e1 * inv, s2 = e2 * inv;

    float4 d0 = ld4(dw + l);
    float4 d1 = ld4(dw + L_ + l);
    float4 d2 = ld4(dw + 2 * L_ + l);
    float4 bb = ld4(bias + l);
    float4 w0 = make_float4(s0 + d0.x, s0 + d0.y, s0 + d0.z, s0 + d0.w);
    float4 w1 = make_float4(s1 + d1.x, s1 + d1.y, s1 + d1.z, s1 + d1.w);
    float4 w2 = make_float4(s2 + d2.x, s2 + d2.y, s2 + d2.z, s2 + d2.w);

    int4 heads = *reinterpret_cast<const int4*>(head + l);

    float4 X[BCHUNK_][3];
    #pragma unroll
    for (int c = 0; c < BCHUNK_; ++c) {
        const float* xb = x + (size_t)(b0 + c) * M_ * L_ + l;
        X[c][0] = ld4(xb);
        X[c][1] = ld4(xb + L_);
        X[c][2] = ld4(xb + 2 * L_);
    }
    #pragma unroll
    for (int c = 0; c < BCHUNK_; ++c) {
        float4 o;
        o.x = X[c][0].x * w0.x + X[c][1].x * w1.x + X[c][2].x * w2.x + bb.x;
        o.y = X[c][0].y * w0.y + X[c][1].y * w1.y + X[c][2].y * w2.y + bb.y;
        o.z = X[c][0].z * w0.z + X[c][1].z * w1.z + X[c][2].z * w2.z + bb.z;
        o.w = X[c][0].w * w0.w + X[c][1].w * w1.w + X[c][2].w * w2.w + bb.w;
        st4(logits + (size_t)(b0 + c) * L_ + l, o);
    }

    // gather (rare: ~4% of labels active)
    int hs[4] = {heads.x, heads.y, heads.z, heads.w};
    #pragma unroll
    for (int c = 0; c < 4; ++c) {
        int a = hs[c];
        while (a >= 0) {
            #pragma unroll
            for (int b = 0; b < BCHUNK_; ++b) {
                unsigned short* xab = xa + (size_t)(b0 + b) * MA_;
                xab[a]          = f2bf(getc(X[b][0], c));
                xab[A_ + a]     = f2bf(getc(X[b][1], c));
                xab[2 * A_ + a] = f2bf(getc(X[b][2], c));
            }
            a = next[a];
        }
    }
}

// GEMM1 split-K MFMA: part[z,b,n] = sum_{k in chunk z} xa[b,k] * hw_bf16[n,k]
__global__ __launch_bounds__(256) void gemm1_mfma(
    const unsigned short* __restrict__ Xa, const unsigned short* __restrict__ W,
    float* __restrict__ part) {
    int tid = threadIdx.x;
    int wave = tid >> 6, lane = tid & 63;
    int row0 = blockIdx.x * 64 + (wave >> 1) * 32;
    int col0 = blockIdx.y * 64 + (wave & 1) * 32;
    int k0 = blockIdx.z * KC1_;
    int lr = lane & 15;
    int lk = (lane >> 4) * 8;
    const unsigned short* pa0 = Xa + (size_t)(row0 + lr) * K1_ + k0 + lk;
    const unsigned short* pa1 = pa0 + (size_t)16 * K1_;
    const unsigned short* pb0 = W + (size_t)(col0 + lr) * K1_ + k0 + lk;
    const unsigned short* pb1 = pb0 + (size_t)16 * K1_;
    f32x4 acc00 = {0.f,0.f,0.f,0.f}, acc01 = {0.f,0.f,0.f,0.f};
    f32x4 acc10 = {0.f,0.f,0.f,0.f}, acc11 = {0.f,0.f,0.f,0.f};
    #pragma unroll 4
    for (int k = 0; k < KC1_; k += 32) {
        bf16x8 a0 = *reinterpret_cast<const bf16x8*>(pa0 + k);
        bf16x8 a1 = *reinterpret_cast<const bf16x8*>(pa1 + k);
        bf16x8 b0 = *reinterpret_cast<const bf16x8*>(pb0 + k);
        bf16x8 b1 = *reinterpret_cast<const bf16x8*>(pb1 + k);
        acc00 = __builtin_amdgcn_mfma_f32_16x16x32_bf16(a0, b0, acc00, 0, 0, 0);
        acc01 = __builtin_amdgcn_mfma_f32_16x16x32_bf16(a0, b1, acc01, 0, 0, 0);
        acc10 = __builtin_amdgcn_mfma_f32_16x16x32_bf16(a1, b0, acc10, 0, 0, 0);
        acc11 = __builtin_amdgcn_mfma_f32_16x16x32_bf16(a1, b1, acc11, 0, 0, 0);
    }
    float* base = part + (size_t)blockIdx.z * B_ * H_;
    #pragma unroll
    for (int j = 0; j < 4; ++j) {
        int r = (lane >> 4) * 4 + j;   // C/D: col=lane&15, row=(lane>>4)*4+j
        base[(size_t)(row0 + r) * H_ + col0 + lr]           = acc00[j];
        base[(size_t)(row0 + r) * H_ + col0 + 16 + lr]      = acc01[j];
        base[(size_t)(row0 + 16 + r) * H_ + col0 + lr]      = acc10[j];
        base[(size_t)(row0 + 16 + r) * H_ + col0 + 16 + lr] = acc11[j];
    }
}

// h[b,n] = bf16(relu(sum_z part[z,b,n] + hb[n]))
__global__ void reduce_relu(const float* __restrict__ part,
                            const float* __restrict__ hb,
                            unsigned short* __restrict__ h) {
    int t = blockIdx.x * blockDim.x + threadIdx.x;
    if (t >= B_ * H_) return;
    int n = t & (H_ - 1);
    float s = hb[n];
    #pragma unroll
    for (int z = 0; z < NZ_; ++z) s += part[(size_t)z * B_ * H_ + t];
    h[t] = f2bf(fmaxf(s, 0.0f));
}

// GEMM2 + fused scatter: logits[b, idx[a]] += alpha*(sum_n h[b,n]*W2[a,n] + b2[a])
// W2 read as fp32, converted in-register. Scatter via atomicAdd (duplicates
// rare; pairwise fp add commutative).
__global__ __launch_bounds__(256) void gemm2_scatter(
    const unsigned short* __restrict__ Hm, const float* __restrict__ W2,
    const float* __restrict__ b2, const float* __restrict__ la,
    const int* __restrict__ idx, float* __restrict__ logits) {
    int tid = threadIdx.x;
    int wave = tid >> 6, lane = tid & 63;
    int row0 = blockIdx.x * 64 + (wave >> 1) * 32;
    int col0 = blockIdx.y * 64 + (wave & 1) * 32;
    int lr = lane & 15;
    int lk = (lane >> 4) * 8;
    const unsigned short* pa0 = Hm + (size_t)(row0 + lr) * H_ + lk;
    const unsigned short* pa1 = pa0 + (size_t)16 * H_;
    const float* pb0 = W2 + (size_t)(col0 + lr) * H_ + lk;
    const float* pb1 = pb0 + (size_t)16 * H_;
    f32x4 acc00 = {0.f,0.f,0.f,0.f}, acc01 = {0.f,0.f,0.f,0.f};
    f32x4 acc10 = {0.f,0.f,0.f,0.f}, acc11 = {0.f,0.f,0.f,0.f};
    #pragma unroll 4
    for (int k = 0; k < H_; k += 32) {
        bf16x8 a0 = *reinterpret_cast<const bf16x8*>(pa0 + k);
        bf16x8 a1 = *reinterpret_cast<const bf16x8*>(pa1 + k);
        bf16x8 b0 = cvt8(ld4(pb0 + k), ld4(pb0 + k + 4));
        bf16x8 b1 = cvt8(ld4(pb1 + k), ld4(pb1 + k + 4));
        acc00 = __builtin_amdgcn_mfma_f32_16x16x32_bf16(a0, b0, acc00, 0, 0, 0);
        acc01 = __builtin_amdgcn_mfma_f32_16x16x32_bf16(a0, b1, acc01, 0, 0, 0);
        acc10 = __builtin_amdgcn_mfma_f32_16x16x32_bf16(a1, b0, acc10, 0, 0, 0);
        acc11 = __builtin_amdgcn_mfma_f32_16x16x32_bf16(a1, b1, acc11, 0, 0, 0);
    }
    float alpha = 0.1f / (1.0f + expf(-la[0]));
    int c0 = col0 + lr, c1 = col0 + 16 + lr;
    int l0 = idx[c0], l1 = idx[c1];
    float bias0 = b2[c0], bias1 = b2[c1];
    #pragma unroll
    for (int j = 0; j < 4; ++j) {
        int r = (lane >> 4) * 4 + j;
        atomicAdd(&logits[(size_t)(row0 + r) * L_ + l0],      alpha * (acc00[j] + bias0));
        atomicAdd(&logits[(size_t)(row0 + r) * L_ + l1],      alpha * (acc01[j] + bias1));
        atomicAdd(&logits[(size_t)(row0 + 16 + r) * L_ + l0], alpha * (acc10[j] + bias0));
        atomicAdd(&logits[(size_t)(row0 + 16 + r) * L_ + l1], alpha * (acc11[j] + bias1));
    }
}

static inline size_t align256(size_t x) { return (x + 255) & ~(size_t)255; }

extern "C" void kernel_launch(void* const* d_in, const int* in_sizes, int n_in,
                              void* d_out, int out_size, void* d_ws, size_t ws_size,
                              hipStream_t stream) {
    const float* x    = (const float*)d_in[0];
    const int*   idx  = (const int*)d_in[1];
    const float* gl   = (const float*)d_in[2];
    const float* dw   = (const float*)d_in[3];
    const float* bias = (const float*)d_in[4];
    const float* la   = (const float*)d_in[5];
    const float* hw   = (const float*)d_in[6];
    const float* hb   = (const float*)d_in[7];
    const float* w2   = (const float*)d_in[8];
    const float* b2   = (const float*)d_in[9];
    float* logits = (float*)d_out;

    char* ws = (char*)d_ws;
    int* head = (int*)ws;                      ws += align256((size_t)L_ * 4);
    int* next = (int*)ws;                      ws += align256((size_t)A_ * 4);
    unsigned short* xa = (unsigned short*)ws;  ws += align256((size_t)B_ * MA_ * 2);
    unsigned short* hwb = (unsigned short*)ws; ws += align256((size_t)H_ * MA_ * 2);
    float* part = (float*)ws;                  ws += align256((size_t)NZ_ * B_ * H_ * 4);
    unsigned short* h = (unsigned short*)ws;   ws += align256((size_t)B_ * H_ * 2);

    init_head<<<(L_ / 4 + 255) / 256, 256, 0, stream>>>(head);
    build_chain<<<(A_ + 255) / 256, 256, 0, stream>>>(idx, head, next);

    f32_to_bf16<<<(H_ * MA_ / 8 + 255) / 256, 256, 0, stream>>>(hw, hwb, H_ * MA_ / 8);

    dim3 g1((L_ / 4 + 255) / 256, B_ / BCHUNK_);
    logits_gather<<<g1, 256, 0, stream>>>(x, gl, dw, bias, head, next, logits, xa);

    gemm1_mfma<<<dim3(B_ / 64, H_ / 64, NZ_), 256, 0, stream>>>(xa, hwb, part);
    reduce_relu<<<(B_ * H_ + 255) / 256, 256, 0, stream>>>(part, hb, h);
    gemm2_scatter<<<dim3(B_ / 64, A_ / 64), 256, 0, stream>>>(h, w2, b2, la, idx, logits);
}

// Round 6
// 202.272 us; speedup vs baseline: 1.2749x; 1.0412x over previous
//
#include <hip/hip_runtime.h>
#include <math.h>

#define B_ 256
#define M_ 3
#define L_ 100000
#define A_ 4096
#define H_ 512
#define MA_ (M_*A_)          // 12288 = K for GEMM1
#define K1_ MA_
#define NZ_ 16               // split-K chunks for GEMM1
#define KC1_ (K1_/NZ_)       // 768
#define BCHUNK_ 4

#define NB_LG_   6272                  // 98 l-blocks * 64 b-chunks
#define NB_LGX_  98                    // l-chunk blocks per b-chunk
#define NB_HW_   3072                  // H_*MA_/8/256
#define NB_W2_   1024                  // A_*H_/8/256

typedef __attribute__((ext_vector_type(8))) short bf16x8;
typedef __attribute__((ext_vector_type(8))) unsigned short u16x8;
typedef __attribute__((ext_vector_type(4))) float f32x4;
typedef __attribute__((ext_vector_type(4))) int i32x4;

static __device__ __forceinline__ f32x4 ld4(const float* p) {
    return *reinterpret_cast<const f32x4*>(p);
}
static __device__ __forceinline__ f32x4 ld4nt(const float* p) {
    return __builtin_nontemporal_load(reinterpret_cast<const f32x4*>(p));
}
static __device__ __forceinline__ void st4nt(float* p, f32x4 v) {
    __builtin_nontemporal_store(v, reinterpret_cast<f32x4*>(p));
}
static __device__ __forceinline__ unsigned short f2bf(float f) {
    unsigned u = __float_as_uint(f);
    unsigned r = (u + 0x7FFFu + ((u >> 16) & 1u)) >> 16;
    return (unsigned short)r;
}

__global__ void init_head(int* __restrict__ head) {
    int i = blockIdx.x * blockDim.x + threadIdx.x;
    if (i < L_ / 4) {
        i32x4 m1 = {-1, -1, -1, -1};
        *reinterpret_cast<i32x4*>(head + i * 4) = m1;
    }
}

// any single winner per label is fine: all readers see the same value next dispatch
__global__ void build_head(const int* __restrict__ idx, int* __restrict__ head) {
    int a = blockIdx.x * blockDim.x + threadIdx.x;
    if (a < A_) head[idx[a]] = a;
}

// Mega-kernel: block ranges do [logits+gather | hw fp32->bf16 | w2 fp32->bf16].
// The conversions hide inside lg's memory slack.
__global__ __launch_bounds__(256) void mega(
    const float* __restrict__ x, const float* __restrict__ gl,
    const float* __restrict__ dw, const float* __restrict__ bias,
    const int* __restrict__ head,
    float* __restrict__ logits, unsigned short* __restrict__ xa,
    const float* __restrict__ hw, unsigned short* __restrict__ hwb,
    const float* __restrict__ w2, unsigned short* __restrict__ w2b) {
    int bid = blockIdx.x;
    int tid = threadIdx.x;

    if (bid >= NB_LG_) {
        // ---- weight conversion blocks ----
        const float* src;
        unsigned short* dst;
        int i;
        if (bid < NB_LG_ + NB_HW_) { src = hw; dst = hwb; i = (bid - NB_LG_) * 256 + tid; }
        else                       { src = w2; dst = w2b; i = (bid - NB_LG_ - NB_HW_) * 256 + tid; }
        f32x4 v0 = ld4nt(src + (size_t)i * 8);
        f32x4 v1 = ld4nt(src + (size_t)i * 8 + 4);
        u16x8 o;
        o[0] = f2bf(v0.x); o[1] = f2bf(v0.y); o[2] = f2bf(v0.z); o[3] = f2bf(v0.w);
        o[4] = f2bf(v1.x); o[5] = f2bf(v1.y); o[6] = f2bf(v1.z); o[7] = f2bf(v1.w);
        *reinterpret_cast<u16x8*>(dst + (size_t)i * 8) = o;
        return;
    }

    // ---- logits + gather ----
    const int L4 = L_ / 4;
    int i = (bid % NB_LGX_) * 256 + tid;
    if (i >= L4) return;
    int l = i * 4;
    int b0 = (bid / NB_LGX_) * BCHUNK_;

    float g0 = gl[0], g1 = gl[1], g2 = gl[2];
    float mx = fmaxf(g0, fmaxf(g1, g2));
    float e0 = expf(g0 - mx), e1 = expf(g1 - mx), e2 = expf(g2 - mx);
    float inv = 1.0f / (e0 + e1 + e2);
    float s0 = e0 * inv, s1 = e1 * inv, s2 = e2 * inv;

    f32x4 d0 = ld4(dw + l);
    f32x4 d1 = ld4(dw + L_ + l);
    f32x4 d2 = ld4(dw + 2 * L_ + l);
    f32x4 bb = ld4(bias + l);
    f32x4 w0 = d0 + s0;
    f32x4 w1 = d1 + s1;
    f32x4 w2v = d2 + s2;

    i32x4 heads = *reinterpret_cast<const i32x4*>(head + l);

    f32x4 X[BCHUNK_][3];
    #pragma unroll
    for (int c = 0; c < BCHUNK_; ++c) {
        const float* xb = x + (size_t)(b0 + c) * M_ * L_ + l;
        X[c][0] = ld4nt(xb);
        X[c][1] = ld4nt(xb + L_);
        X[c][2] = ld4nt(xb + 2 * L_);
    }
    #pragma unroll
    for (int c = 0; c < BCHUNK_; ++c) {
        f32x4 o = X[c][0] * w0 + X[c][1] * w1 + X[c][2] * w2v + bb;
        st4nt(logits + (size_t)(b0 + c) * L_ + l, o);
    }

    // gather: only the winning a per label writes; dups fixed by fixup kernel.
    #pragma unroll
    for (int c = 0; c < 4; ++c) {
        int a = heads[c];
        if (a >= 0) {
            #pragma unroll
            for (int b = 0; b < BCHUNK_; ++b) {
                unsigned short* xab = xa + (size_t)(b0 + b) * MA_;
                xab[a]          = f2bf(X[b][0][c]);
                xab[A_ + a]     = f2bf(X[b][1][c]);
                xab[2 * A_ + a] = f2bf(X[b][2][c]);
            }
        }
    }
}

// duplicate columns copy from their label's winner column (~80 dups total)
__global__ void fixup(const int* __restrict__ idx, const int* __restrict__ head,
                      unsigned short* __restrict__ xa) {
    int t = blockIdx.x * blockDim.x + threadIdx.x;
    if (t >= B_ * A_) return;
    int a = t & (A_ - 1);
    int b = t >> 12;
    int ha = head[idx[a]];
    if (ha == a) return;
    unsigned short* xab = xa + (size_t)b * MA_;
    xab[a]          = xab[ha];
    xab[A_ + a]     = xab[A_ + ha];
    xab[2 * A_ + a] = xab[2 * A_ + ha];
}

// GEMM1 split-K MFMA: part[z,b,n] = sum_{k in chunk z} xa[b,k] * hwb[n,k]
__global__ __launch_bounds__(256) void gemm1_mfma(
    const unsigned short* __restrict__ Xa, const unsigned short* __restrict__ W,
    float* __restrict__ part) {
    int tid = threadIdx.x;
    int wave = tid >> 6, lane = tid & 63;
    int row0 = blockIdx.x * 64 + (wave >> 1) * 32;
    int col0 = blockIdx.y * 64 + (wave & 1) * 32;
    int k0 = blockIdx.z * KC1_;
    int lr = lane & 15;
    int lk = (lane >> 4) * 8;
    const unsigned short* pa0 = Xa + (size_t)(row0 + lr) * K1_ + k0 + lk;
    const unsigned short* pa1 = pa0 + (size_t)16 * K1_;
    const unsigned short* pb0 = W + (size_t)(col0 + lr) * K1_ + k0 + lk;
    const unsigned short* pb1 = pb0 + (size_t)16 * K1_;
    f32x4 acc00 = {0.f,0.f,0.f,0.f}, acc01 = {0.f,0.f,0.f,0.f};
    f32x4 acc10 = {0.f,0.f,0.f,0.f}, acc11 = {0.f,0.f,0.f,0.f};
    #pragma unroll 4
    for (int k = 0; k < KC1_; k += 32) {
        bf16x8 a0 = *reinterpret_cast<const bf16x8*>(pa0 + k);
        bf16x8 a1 = *reinterpret_cast<const bf16x8*>(pa1 + k);
        bf16x8 b0 = *reinterpret_cast<const bf16x8*>(pb0 + k);
        bf16x8 b1 = *reinterpret_cast<const bf16x8*>(pb1 + k);
        acc00 = __builtin_amdgcn_mfma_f32_16x16x32_bf16(a0, b0, acc00, 0, 0, 0);
        acc01 = __builtin_amdgcn_mfma_f32_16x16x32_bf16(a0, b1, acc01, 0, 0, 0);
        acc10 = __builtin_amdgcn_mfma_f32_16x16x32_bf16(a1, b0, acc10, 0, 0, 0);
        acc11 = __builtin_amdgcn_mfma_f32_16x16x32_bf16(a1, b1, acc11, 0, 0, 0);
    }
    float* base = part + (size_t)blockIdx.z * B_ * H_;
    #pragma unroll
    for (int j = 0; j < 4; ++j) {
        int r = (lane >> 4) * 4 + j;   // C/D: col=lane&15, row=(lane>>4)*4+j
        base[(size_t)(row0 + r) * H_ + col0 + lr]           = acc00[j];
        base[(size_t)(row0 + r) * H_ + col0 + 16 + lr]      = acc01[j];
        base[(size_t)(row0 + 16 + r) * H_ + col0 + lr]      = acc10[j];
        base[(size_t)(row0 + 16 + r) * H_ + col0 + 16 + lr] = acc11[j];
    }
}

// h[b,n] = bf16(relu(sum_z part[z,b,n] + hb[n]))
__global__ void reduce_relu(const float* __restrict__ part,
                            const float* __restrict__ hb,
                            unsigned short* __restrict__ h) {
    int t = blockIdx.x * blockDim.x + threadIdx.x;
    if (t >= B_ * H_) return;
    int n = t & (H_ - 1);
    float s = hb[n];
    #pragma unroll
    for (int z = 0; z < NZ_; ++z) s += part[(size_t)z * B_ * H_ + t];
    h[t] = f2bf(fmaxf(s, 0.0f));
}

// GEMM2 (bf16 weights) + fused atomic scatter into logits.
__global__ __launch_bounds__(256) void gemm2_scatter(
    const unsigned short* __restrict__ Hm, const unsigned short* __restrict__ W2,
    const float* __restrict__ b2, const float* __restrict__ la,
    const int* __restrict__ idx, float* __restrict__ logits) {
    int tid = threadIdx.x;
    int wave = tid >> 6, lane = tid & 63;
    int row0 = blockIdx.x * 64 + (wave >> 1) * 32;
    int col0 = blockIdx.y * 64 + (wave & 1) * 32;
    int lr = lane & 15;
    int lk = (lane >> 4) * 8;
    const unsigned short* pa0 = Hm + (size_t)(row0 + lr) * H_ + lk;
    const unsigned short* pa1 = pa0 + (size_t)16 * H_;
    const unsigned short* pb0 = W2 + (size_t)(col0 + lr) * H_ + lk;
    const unsigned short* pb1 = pb0 + (size_t)16 * H_;
    f32x4 acc00 = {0.f,0.f,0.f,0.f}, acc01 = {0.f,0.f,0.f,0.f};
    f32x4 acc10 = {0.f,0.f,0.f,0.f}, acc11 = {0.f,0.f,0.f,0.f};
    #pragma unroll 4
    for (int k = 0; k < H_; k += 32) {
        bf16x8 a0 = *reinterpret_cast<const bf16x8*>(pa0 + k);
        bf16x8 a1 = *reinterpret_cast<const bf16x8*>(pa1 + k);
        bf16x8 b0 = *reinterpret_cast<const bf16x8*>(pb0 + k);
        bf16x8 b1 = *reinterpret_cast<const bf16x8*>(pb1 + k);
        acc00 = __builtin_amdgcn_mfma_f32_16x16x32_bf16(a0, b0, acc00, 0, 0, 0);
        acc01 = __builtin_amdgcn_mfma_f32_16x16x32_bf16(a0, b1, acc01, 0, 0, 0);
        acc10 = __builtin_amdgcn_mfma_f32_16x16x32_bf16(a1, b0, acc10, 0, 0, 0);
        acc11 = __builtin_amdgcn_mfma_f32_16x16x32_bf16(a1, b1, acc11, 0, 0, 0);
    }
    float alpha = 0.1f / (1.0f + expf(-la[0]));
    int c0 = col0 + lr, c1 = col0 + 16 + lr;
    int l0 = idx[c0], l1 = idx[c1];
    float bias0 = b2[c0], bias1 = b2[c1];
    #pragma unroll
    for (int j = 0; j < 4; ++j) {
        int r = (lane >> 4) * 4 + j;
        atomicAdd(&logits[(size_t)(row0 + r) * L_ + l0],      alpha * (acc00[j] + bias0));
        atomicAdd(&logits[(size_t)(row0 + r) * L_ + l1],      alpha * (acc01[j] + bias1));
        atomicAdd(&logits[(size_t)(row0 + 16 + r) * L_ + l0], alpha * (acc10[j] + bias0));
        atomicAdd(&logits[(size_t)(row0 + 16 + r) * L_ + l1], alpha * (acc11[j] + bias1));
    }
}

static inline size_t align256(size_t x) { return (x + 255) & ~(size_t)255; }

extern "C" void kernel_launch(void* const* d_in, const int* in_sizes, int n_in,
                              void* d_out, int out_size, void* d_ws, size_t ws_size,
                              hipStream_t stream) {
    const float* x    = (const float*)d_in[0];
    const int*   idx  = (const int*)d_in[1];
    const float* gl   = (const float*)d_in[2];
    const float* dw   = (const float*)d_in[3];
    const float* bias = (const float*)d_in[4];
    const float* la   = (const float*)d_in[5];
    const float* hw   = (const float*)d_in[6];
    const float* hb   = (const float*)d_in[7];
    const float* w2   = (const float*)d_in[8];
    const float* b2   = (const float*)d_in[9];
    float* logits = (float*)d_out;

    char* ws = (char*)d_ws;
    int* head = (int*)ws;                      ws += align256((size_t)L_ * 4);
    unsigned short* xa = (unsigned short*)ws;  ws += align256((size_t)B_ * MA_ * 2);
    unsigned short* hwb = (unsigned short*)ws; ws += align256((size_t)H_ * MA_ * 2);
    unsigned short* w2b = (unsigned short*)ws; ws += align256((size_t)A_ * H_ * 2);
    float* part = (float*)ws;                  ws += align256((size_t)NZ_ * B_ * H_ * 4);
    unsigned short* h = (unsigned short*)ws;   ws += align256((size_t)B_ * H_ * 2);

    init_head<<<(L_ / 4 + 255) / 256, 256, 0, stream>>>(head);
    build_head<<<(A_ + 255) / 256, 256, 0, stream>>>(idx, head);

    mega<<<NB_LG_ + NB_HW_ + NB_W2_, 256, 0, stream>>>(
        x, gl, dw, bias, head, logits, xa, hw, hwb, w2, w2b);

    fixup<<<(B_ * A_ + 255) / 256, 256, 0, stream>>>(idx, head, xa);

    gemm1_mfma<<<dim3(B_ / 64, H_ / 64, NZ_), 256, 0, stream>>>(xa, hwb, part);
    reduce_relu<<<(B_ * H_ + 255) / 256, 256, 0, stream>>>(part, hb, h);
    gemm2_scatter<<<dim3(B_ / 64, A_ / 64), 256, 0, stream>>>(h, w2b, b2, la, idx, logits);
}